// Round 2
// baseline (273.789 us; speedup 1.0000x reference)
//
#include <hip/hip_runtime.h>
#include <hip/hip_cooperative_groups.h>

namespace cg = cooperative_groups;

#define BLOCK 256
#define SUBS  1024                // sub-chunks (4 steps each) per block
#define SPAN  4096                // steps per block
#define CHUNK 16                  // fallback-path chunk

// Affine transform x -> [[p,q],[r,s]] x + [u,v]
struct Xf { float p, q, r, s, u, v; };

__device__ __forceinline__ Xf xf_id() {
    Xf t; t.p = 1.f; t.q = 0.f; t.r = 0.f; t.s = 1.f; t.u = 0.f; t.v = 0.f;
    return t;
}

// result = L ∘ E  (E applied first, then L)
__device__ __forceinline__ Xf xf_compose(const Xf& E, const Xf& L) {
    Xf o;
    o.p = L.p * E.p + L.q * E.r;
    o.q = L.p * E.q + L.q * E.s;
    o.r = L.r * E.p + L.s * E.r;
    o.s = L.r * E.q + L.s * E.s;
    o.u = L.p * E.u + L.q * E.v + L.u;
    o.v = L.r * E.u + L.s * E.v + L.v;
    return o;
}

struct Par {
    float M11, M12, M21, Kx;   // fixed M entries, Kx = M12*M21
    float c0, c1;              // M22 = c0 + c1*rRia ; c1 = dt/C_in
    float cTo0, cIrr0, cQi0;   // bu0 coefficients
    float cIrr1, cQi1;         // bu1 coefficients
};

__device__ __forceinline__ Par make_par(
    const float* pRie, const float* pRea, const float* pCin, const float* pCen,
    const float* pAsi, const float* pAse, const float* pAii, const float* pAie)
{
    const float dt = 1800.0f;
    const float GA = 0.76f * 41.3f;  // g * Az
    float R_ie = *pRie, R_ea = *pRea, C_in = *pCin, C_en = *pCen;
    float asi = *pAsi, ase = *pAse, aii = *pAii, aie = *pAie;
    Par P;
    float iRie = 1.0f / R_ie;
    P.M11 = 1.0f + dt * (1.0f / R_ea + iRie) / C_en;
    P.M12 = -(dt * iRie) / C_en;
    P.M21 = -(dt * iRie) / C_in;
    P.Kx  = P.M12 * P.M21;
    P.c1  = dt / C_in;
    P.c0  = 1.0f + P.c1 * iRie;
    P.cTo0  = dt / (C_en * R_ea);
    P.cIrr0 = dt * ase * GA / C_en;
    P.cQi0  = dt * aie / C_en;
    P.cIrr1 = dt * asi * GA / C_in;
    P.cQi1  = dt * aii / C_in;
    return P;
}

// ---- skewed LDS addressing (conflict-free for both access phases) ----
__device__ __forceinline__ void storeA(float* A, int s, const Xf& v) {
    float* b = A + 6 * s + (s >> 2);
    b[0] = v.p; b[1] = v.q; b[2] = v.r; b[3] = v.s; b[4] = v.u; b[5] = v.v;
}
__device__ __forceinline__ Xf loadA(const float* A, int s) {
    const float* b = A + 6 * s + (s >> 2);
    Xf v; v.p = b[0]; v.q = b[1]; v.r = b[2]; v.s = b[3]; v.u = b[4]; v.v = b[5];
    return v;
}

// scan buffer, stride 7 (gcd(7,32)=1)
__device__ __forceinline__ void sm_store(float* sm, int i, const Xf& v) {
    float* b = sm + i * 7;
    b[0] = v.p; b[1] = v.q; b[2] = v.r; b[3] = v.s; b[4] = v.u; b[5] = v.v;
}
__device__ __forceinline__ Xf sm_load(const float* sm, int i) {
    const float* b = sm + i * 7;
    Xf v; v.p = b[0]; v.q = b[1]; v.r = b[2]; v.s = b[3]; v.u = b[4]; v.v = b[5];
    return v;
}

// Inclusive Hillis-Steele scan over BLOCK transforms; sm holds inclusives on exit
__device__ __forceinline__ Xf block_scan(Xf v, float* sm) {
    const int t = threadIdx.x;
    sm_store(sm, t, v);
    __syncthreads();
    for (int off = 1; off < BLOCK; off <<= 1) {
        Xf e;
        bool has = (t >= off);
        if (has) e = sm_load(sm, t - off);
        __syncthreads();
        if (has) { v = xf_compose(e, v); sm_store(sm, t, v); }
        __syncthreads();
    }
    return v;
}

// =====================  fused single-pass cooperative kernel  ================
__global__ __launch_bounds__(BLOCK, 4) void k_fused(
    const float* __restrict__ To, const float* __restrict__ Irr,
    const float* __restrict__ Qi, const float* __restrict__ Qa,
    const float* __restrict__ Ra,
    const float* pRie, const float* pRea, const float* pCin, const float* pCen,
    const float* pAsi, const float* pAse, const float* pAii, const float* pAie,
    const float* pTin0, Xf* __restrict__ ws, float* __restrict__ out, int N)
{
    __shared__ float smA[6400];          // 25.6 KB: sub-chunk xfs, later states
    __shared__ float smScan[BLOCK * 7];  // 7 KB scan buffer
    const int t = threadIdx.x;
    const int b = blockIdx.x;
    const int blockBase = b * SPAN;
    Par P = make_par(pRie, pRea, pCin, pCen, pAsi, pAse, pAii, pAie);

    float rRv[4][4], b0v[4][4], b1v[4][4];

    // ---------- phase 1: dense loads, sub-chunk transforms ----------
#pragma unroll
    for (int k = 0; k < 4; ++k) {
        const int s = t + BLOCK * k;            // sub-chunk index in block
        const int gstep = blockBase + s * 4;    // first step of sub-chunk
        float tox[4], irx[4], qix[4], qax[4], rax[4];
        if (gstep + 4 <= N) {
            float4 v;
            v = *(const float4*)(To  + gstep); tox[0]=v.x; tox[1]=v.y; tox[2]=v.z; tox[3]=v.w;
            v = *(const float4*)(Irr + gstep); irx[0]=v.x; irx[1]=v.y; irx[2]=v.z; irx[3]=v.w;
            v = *(const float4*)(Qi  + gstep); qix[0]=v.x; qix[1]=v.y; qix[2]=v.z; qix[3]=v.w;
            v = *(const float4*)(Qa  + gstep); qax[0]=v.x; qax[1]=v.y; qax[2]=v.z; qax[3]=v.w;
            v = *(const float4*)(Ra  + gstep); rax[0]=v.x; rax[1]=v.y; rax[2]=v.z; rax[3]=v.w;
        } else {
#pragma unroll
            for (int j = 0; j < 4; ++j) {
                int gi = gstep + j; bool val = gi < N;
                tox[j] = val ? To[gi]  : 0.f;
                irx[j] = val ? Irr[gi] : 0.f;
                qix[j] = val ? Qi[gi]  : 0.f;
                qax[j] = val ? Qa[gi]  : 0.f;
                rax[j] = val ? Ra[gi]  : 1.f;
            }
        }
        Xf sub = xf_id();
#pragma unroll
        for (int j = 0; j < 4; ++j) {
            float rR = __builtin_amdgcn_rcpf(fmaxf(rax[j], 1e-6f));
            float b0 = P.cTo0 * tox[j] + P.cIrr0 * irx[j] + P.cQi0 * qix[j];
            float b1 = P.c1 * fmaf(tox[j], rR, qax[j]) + P.cIrr1 * irx[j] + P.cQi1 * qix[j];
            rRv[k][j] = rR; b0v[k][j] = b0; b1v[k][j] = b1;
            if (gstep + j < N) {
                float M22 = fmaf(P.c1, rR, P.c0);
                float det = fmaf(P.M11, M22, -P.Kx);
                float rd  = __builtin_amdgcn_rcpf(det);
                Xf T;
                T.p =  M22 * rd;
                T.q = -P.M12 * rd;
                T.r = -P.M21 * rd;
                T.s =  P.M11 * rd;
                T.u = T.p * b0 + T.q * b1;
                T.v = T.r * b0 + T.s * b1;
                sub = xf_compose(sub, T);
            }
        }
        storeA(smA, s, sub);
    }
    __syncthreads();

    // thread-level compose (ordered) + intra-block scan
    Xf w = xf_id();
#pragma unroll
    for (int j = 0; j < 4; ++j) w = xf_compose(w, loadA(smA, 4 * t + j));
    Xf incl = block_scan(w, smScan);
    Xf E = (t > 0) ? sm_load(smScan, t - 1) : xf_id();   // exclusive thread prefix
    if (t == BLOCK - 1) ws[b] = incl;                    // block aggregate

    cg::this_grid().sync();

    // ---------- spine: masked scan of block aggregates -> block prefix ----------
    Xf acc = xf_id();
#pragma unroll
    for (int j = 0; j < 4; ++j) {
        int i = 4 * t + j;
        if (i < b) { Xf g = ws[i]; acc = xf_compose(acc, g); }
    }
    block_scan(acc, smScan);
    Xf Pt = sm_load(smScan, BLOCK - 1);   // transform of blocks [0, b)
    float T0 = *pTin0;
    float xb0 = (Pt.p + Pt.q) * T0 + Pt.u;
    float xb1 = (Pt.r + Pt.s) * T0 + Pt.v;

    // thread-start state, then per-sub-chunk start states for s = 4t..4t+3
    float sx0 = E.p * xb0 + E.q * xb1 + E.u;
    float sx1 = E.r * xb0 + E.s * xb1 + E.v;
    float st0[4], st1[4];
#pragma unroll
    for (int j = 0; j < 4; ++j) {
        st0[j] = sx0; st1[j] = sx1;
        Xf S = loadA(smA, 4 * t + j);
        float n0 = S.p * sx0 + S.q * sx1 + S.u;
        float n1 = S.r * sx0 + S.s * sx1 + S.v;
        sx0 = n0; sx1 = n1;
    }
    __syncthreads();   // all reads of smA transforms done before overwrite
#pragma unroll
    for (int j = 0; j < 4; ++j) {
        int s = 4 * t + j;
        float* pS = smA + 2 * s + (s >> 3);
        pS[0] = st0[j]; pS[1] = st1[j];
    }
    __syncthreads();

    // ---------- phase 2: replay from registers, dense stores ----------
#pragma unroll
    for (int k = 0; k < 4; ++k) {
        const int s = t + BLOCK * k;
        const float* pS = smA + 2 * s + (s >> 3);
        float x0 = pS[0], x1 = pS[1];
        const int gstep = blockBase + s * 4;
        float ov[4];
#pragma unroll
        for (int j = 0; j < 4; ++j) {
            float rR  = rRv[k][j];
            float M22 = fmaf(P.c1, rR, P.c0);
            float det = fmaf(P.M11, M22, -P.Kx);
            float rd  = __builtin_amdgcn_rcpf(det);
            float r0 = x0 + b0v[k][j];
            float r1 = x1 + b1v[k][j];
            float n0 = (M22 * r0 - P.M12 * r1) * rd;
            float n1 = (P.M11 * r1 - P.M21 * r0) * rd;
            x0 = n0; x1 = n1; ov[j] = n1;
        }
        if (gstep + 4 <= N) {
            float4 o; o.x = ov[0]; o.y = ov[1]; o.z = ov[2]; o.w = ov[3];
            *(float4*)(out + gstep) = o;
        } else {
#pragma unroll
            for (int j = 0; j < 4; ++j) { int gi = gstep + j; if (gi < N) out[gi] = ov[j]; }
        }
    }
}

// =====================  fallback 3-kernel path (known-good)  ================
__device__ __forceinline__ Xf gen_step(const Par& P, float To, float Irr,
                                       float Qi, float Qa, float Ra)
{
    float rR  = __builtin_amdgcn_rcpf(fmaxf(Ra, 1e-6f));
    float M22 = fmaf(P.c1, rR, P.c0);
    float det = fmaf(P.M11, M22, -P.Kx);
    float rd  = __builtin_amdgcn_rcpf(det);
    float bu0 = P.cTo0 * To + P.cIrr0 * Irr + P.cQi0 * Qi;
    float bu1 = P.c1 * fmaf(To, rR, Qa) + P.cIrr1 * Irr + P.cQi1 * Qi;
    Xf T;
    T.p =  M22 * rd;
    T.q = -P.M12 * rd;
    T.r = -P.M21 * rd;
    T.s =  P.M11 * rd;
    T.u = T.p * bu0 + T.q * bu1;
    T.v = T.r * bu0 + T.s * bu1;
    return T;
}

__device__ __forceinline__ Xf chunk_xf(const Par& P,
    const float* __restrict__ To, const float* __restrict__ Irr,
    const float* __restrict__ Qi, const float* __restrict__ Qa,
    const float* __restrict__ Ra, int base, int N)
{
    Xf v = xf_id();
    if (base + CHUNK <= N) {
#pragma unroll
        for (int g = 0; g < CHUNK / 4; ++g) {
            const int o = base + g * 4;
            float4 t  = *(const float4*)(To + o);
            float4 ir = *(const float4*)(Irr + o);
            float4 qi = *(const float4*)(Qi + o);
            float4 qa = *(const float4*)(Qa + o);
            float4 ra = *(const float4*)(Ra + o);
            v = xf_compose(v, gen_step(P, t.x, ir.x, qi.x, qa.x, ra.x));
            v = xf_compose(v, gen_step(P, t.y, ir.y, qi.y, qa.y, ra.y));
            v = xf_compose(v, gen_step(P, t.z, ir.z, qi.z, qa.z, ra.z));
            v = xf_compose(v, gen_step(P, t.w, ir.w, qi.w, qa.w, ra.w));
        }
    } else {
        for (int j = 0; j < CHUNK; ++j) {
            int i = base + j;
            if (i < N)
                v = xf_compose(v, gen_step(P, To[i], Irr[i], Qi[i], Qa[i], Ra[i]));
        }
    }
    return v;
}

__global__ __launch_bounds__(BLOCK) void k_blocksum(
    const float* __restrict__ To, const float* __restrict__ Irr,
    const float* __restrict__ Qi, const float* __restrict__ Qa,
    const float* __restrict__ Ra,
    const float* pRie, const float* pRea, const float* pCin, const float* pCen,
    const float* pAsi, const float* pAse, const float* pAii, const float* pAie,
    Xf* __restrict__ blkX, int N)
{
    Par P = make_par(pRie, pRea, pCin, pCen, pAsi, pAse, pAii, pAie);
    int base = blockIdx.x * (BLOCK * CHUNK) + threadIdx.x * CHUNK;
    Xf v = chunk_xf(P, To, Irr, Qi, Qa, Ra, base, N);
    __shared__ float sm[BLOCK * 7];
    v = block_scan(v, sm);
    if (threadIdx.x == BLOCK - 1) blkX[blockIdx.x] = v;
}

__global__ __launch_bounds__(BLOCK) void k_mid(
    const Xf* __restrict__ blkX, float2* __restrict__ blkSt,
    const float* pTin0, int NB)
{
    const int t = threadIdx.x;
    const int ser = (NB + BLOCK - 1) / BLOCK;
    const int base = t * ser;
    Xf acc = xf_id();
    for (int j = 0; j < ser; ++j) {
        int i = base + j;
        if (i < NB) acc = xf_compose(acc, blkX[i]);
    }
    __shared__ float sm[BLOCK * 7];
    block_scan(acc, sm);
    Xf E = xf_id();
    if (t > 0) E = sm_load(sm, t - 1);
    float T0 = *pTin0;
    float x0 = (E.p + E.q) * T0 + E.u;
    float x1 = (E.r + E.s) * T0 + E.v;
    for (int j = 0; j < ser; ++j) {
        int i = base + j;
        if (i < NB) {
            blkSt[i] = make_float2(x0, x1);
            Xf T = blkX[i];
            float n0 = T.p * x0 + T.q * x1 + T.u;
            float n1 = T.r * x0 + T.s * x1 + T.v;
            x0 = n0; x1 = n1;
        }
    }
}

__global__ __launch_bounds__(BLOCK) void k_emit(
    const float* __restrict__ To, const float* __restrict__ Irr,
    const float* __restrict__ Qi, const float* __restrict__ Qa,
    const float* __restrict__ Ra,
    const float* pRie, const float* pRea, const float* pCin, const float* pCen,
    const float* pAsi, const float* pAse, const float* pAii, const float* pAie,
    const float2* __restrict__ blkSt, float* __restrict__ out, int N)
{
    Par P = make_par(pRie, pRea, pCin, pCen, pAsi, pAse, pAii, pAie);
    const int t = threadIdx.x;
    int base = blockIdx.x * (BLOCK * CHUNK) + t * CHUNK;
    Xf v = chunk_xf(P, To, Irr, Qi, Qa, Ra, base, N);
    __shared__ float sm[BLOCK * 7];
    block_scan(v, sm);
    Xf E = xf_id();
    if (t > 0) E = sm_load(sm, t - 1);
    float2 B = blkSt[blockIdx.x];
    float x0 = E.p * B.x + E.q * B.y + E.u;
    float x1 = E.r * B.x + E.s * B.y + E.v;
    for (int j = 0; j < CHUNK; ++j) {
        int i = base + j;
        if (i < N) {
            Xf T = gen_step(P, To[i], Irr[i], Qi[i], Qa[i], Ra[i]);
            float n0 = T.p * x0 + T.q * x1 + T.u;
            float n1 = T.r * x0 + T.s * x1 + T.v;
            x0 = n0; x1 = n1;
            out[i] = n1;
        }
    }
}

// ============================  launcher  ====================================
extern "C" void kernel_launch(void* const* d_in, const int* in_sizes, int n_in,
                              void* d_out, int out_size, void* d_ws, size_t ws_size,
                              hipStream_t stream)
{
    (void)n_in; (void)out_size; (void)ws_size;
    const float* pRie = (const float*)d_in[0];
    const float* pRea = (const float*)d_in[1];
    const float* pCin = (const float*)d_in[2];
    const float* pCen = (const float*)d_in[3];
    const float* pAsi = (const float*)d_in[4];
    const float* pAse = (const float*)d_in[5];
    const float* pAii = (const float*)d_in[6];
    const float* pAie = (const float*)d_in[7];
    const float* pTin0 = (const float*)d_in[8];
    const float* To  = (const float*)d_in[9];
    const float* Irr = (const float*)d_in[10];
    const float* Qi  = (const float*)d_in[11];
    const float* Qa  = (const float*)d_in[12];
    const float* Ra  = (const float*)d_in[13];
    float* outp = (float*)d_out;
    int N = in_sizes[9];
    if (N <= 0) return;

    const int NB = (N + SPAN - 1) / SPAN;
    Xf* ws = (Xf*)d_ws;

    // decide path: fused cooperative kernel only if the whole grid is co-resident
    int dev = 0;
    hipGetDevice(&dev);
    int numCU = 0;
    hipDeviceGetAttribute(&numCU, hipDeviceAttributeMultiprocessorCount, dev);
    int maxb = 0;
    hipOccupancyMaxActiveBlocksPerMultiprocessor(&maxb, (const void*)k_fused, BLOCK, 0);
    bool coop = (maxb > 0) && ((long long)maxb * (long long)numCU >= (long long)NB);

    if (coop) {
        void* args[17];
        args[0]  = (void*)&To;   args[1]  = (void*)&Irr;  args[2]  = (void*)&Qi;
        args[3]  = (void*)&Qa;   args[4]  = (void*)&Ra;
        args[5]  = (void*)&pRie; args[6]  = (void*)&pRea; args[7]  = (void*)&pCin;
        args[8]  = (void*)&pCen; args[9]  = (void*)&pAsi; args[10] = (void*)&pAse;
        args[11] = (void*)&pAii; args[12] = (void*)&pAie; args[13] = (void*)&pTin0;
        args[14] = (void*)&ws;   args[15] = (void*)&outp; args[16] = (void*)&N;
        hipLaunchCooperativeKernel((void*)k_fused, dim3(NB), dim3(BLOCK), args, 0, stream);
    } else {
        const int NCH  = (N + CHUNK - 1) / CHUNK;
        const int NB3  = (NCH + BLOCK - 1) / BLOCK;
        Xf* blkX = (Xf*)d_ws;
        size_t off = ((size_t)NB3 * sizeof(Xf) + 255) & ~(size_t)255;
        float2* blkSt = (float2*)((char*)d_ws + off);
        k_blocksum<<<NB3, BLOCK, 0, stream>>>(To, Irr, Qi, Qa, Ra,
            pRie, pRea, pCin, pCen, pAsi, pAse, pAii, pAie, blkX, N);
        k_mid<<<1, BLOCK, 0, stream>>>(blkX, blkSt, pTin0, NB3);
        k_emit<<<NB3, BLOCK, 0, stream>>>(To, Irr, Qi, Qa, Ra,
            pRie, pRea, pCin, pCen, pAsi, pAse, pAii, pAie, blkSt, outp, N);
    }
}

// Round 3
// 47.432 us; speedup vs baseline: 5.7722x; 5.7722x over previous
//
#include <hip/hip_runtime.h>

#define BLOCK 256
#define SPAN  4096                // steps per block (1024 sub-chunks of 4)

// Affine transform x -> [[p,q],[r,s]] x + [u,v]
struct Xf { float p, q, r, s, u, v; };

__device__ __forceinline__ Xf xf_id() {
    Xf t; t.p = 1.f; t.q = 0.f; t.r = 0.f; t.s = 1.f; t.u = 0.f; t.v = 0.f;
    return t;
}

// result = L ∘ E  (E applied first, then L)
__device__ __forceinline__ Xf xf_compose(const Xf& E, const Xf& L) {
    Xf o;
    o.p = L.p * E.p + L.q * E.r;
    o.q = L.p * E.q + L.q * E.s;
    o.r = L.r * E.p + L.s * E.r;
    o.s = L.r * E.q + L.s * E.s;
    o.u = L.p * E.u + L.q * E.v + L.u;
    o.v = L.r * E.u + L.s * E.v + L.v;
    return o;
}

struct Par {
    float M11, M12, M21, Kx;   // fixed M entries, Kx = M12*M21
    float c0, c1;              // M22 = c0 + c1*rRia ; c1 = dt/C_in
    float cTo0, cIrr0, cQi0;   // bu0 coefficients
    float cIrr1, cQi1;         // bu1 coefficients
};

__device__ __forceinline__ Par make_par(
    const float* pRie, const float* pRea, const float* pCin, const float* pCen,
    const float* pAsi, const float* pAse, const float* pAii, const float* pAie)
{
    const float dt = 1800.0f;
    const float GA = 0.76f * 41.3f;  // g * Az
    float R_ie = *pRie, R_ea = *pRea, C_in = *pCin, C_en = *pCen;
    float asi = *pAsi, ase = *pAse, aii = *pAii, aie = *pAie;
    Par P;
    float iRie = 1.0f / R_ie;
    P.M11 = 1.0f + dt * (1.0f / R_ea + iRie) / C_en;
    P.M12 = -(dt * iRie) / C_en;
    P.M21 = -(dt * iRie) / C_in;
    P.Kx  = P.M12 * P.M21;
    P.c1  = dt / C_in;
    P.c0  = 1.0f + P.c1 * iRie;
    P.cTo0  = dt / (C_en * R_ea);
    P.cIrr0 = dt * ase * GA / C_en;
    P.cQi0  = dt * aie / C_en;
    P.cIrr1 = dt * asi * GA / C_in;
    P.cQi1  = dt * aii / C_in;
    return P;
}

// ---- skewed LDS addressing for sub-chunk transforms ----
__device__ __forceinline__ void storeA(float* A, int s, const Xf& v) {
    float* b = A + 6 * s + (s >> 2);
    b[0] = v.p; b[1] = v.q; b[2] = v.r; b[3] = v.s; b[4] = v.u; b[5] = v.v;
}
__device__ __forceinline__ Xf loadA(const float* A, int s) {
    const float* b = A + 6 * s + (s >> 2);
    Xf v; v.p = b[0]; v.q = b[1]; v.r = b[2]; v.s = b[3]; v.u = b[4]; v.v = b[5];
    return v;
}

// scan buffer, stride 7 (gcd(7,32)=1)
__device__ __forceinline__ void sm_store(float* sm, int i, const Xf& v) {
    float* b = sm + i * 7;
    b[0] = v.p; b[1] = v.q; b[2] = v.r; b[3] = v.s; b[4] = v.u; b[5] = v.v;
}
__device__ __forceinline__ Xf sm_load(const float* sm, int i) {
    const float* b = sm + i * 7;
    Xf v; v.p = b[0]; v.q = b[1]; v.r = b[2]; v.s = b[3]; v.u = b[4]; v.v = b[5];
    return v;
}

// Inclusive Hillis-Steele scan over BLOCK transforms; sm holds inclusives on exit
__device__ __forceinline__ Xf block_scan(Xf v, float* sm) {
    const int t = threadIdx.x;
    sm_store(sm, t, v);
    __syncthreads();
    for (int off = 1; off < BLOCK; off <<= 1) {
        Xf e;
        bool has = (t >= off);
        if (has) e = sm_load(sm, t - off);
        __syncthreads();
        if (has) { v = xf_compose(e, v); sm_store(sm, t, v); }
        __syncthreads();
    }
    return v;
}

// =============== k1: per-block aggregate transform (dense loads) ============
__global__ __launch_bounds__(BLOCK, 4) void k_blocksum(
    const float* __restrict__ To, const float* __restrict__ Irr,
    const float* __restrict__ Qi, const float* __restrict__ Qa,
    const float* __restrict__ Ra,
    const float* pRie, const float* pRea, const float* pCin, const float* pCen,
    const float* pAsi, const float* pAse, const float* pAii, const float* pAie,
    Xf* __restrict__ blkX, int N)
{
    __shared__ float smA[6400];          // 1024 sub-chunk transforms, skewed
    __shared__ float smScan[BLOCK * 7];
    const int t = threadIdx.x;
    const int blockBase = blockIdx.x * SPAN;
    Par P = make_par(pRie, pRea, pCin, pCen, pAsi, pAse, pAii, pAie);

#pragma unroll
    for (int k = 0; k < 4; ++k) {
        const int s = t + BLOCK * k;
        const int gstep = blockBase + s * 4;
        float tox[4], irx[4], qix[4], qax[4], rax[4];
        if (gstep + 4 <= N) {
            float4 v;
            v = *(const float4*)(To  + gstep); tox[0]=v.x; tox[1]=v.y; tox[2]=v.z; tox[3]=v.w;
            v = *(const float4*)(Irr + gstep); irx[0]=v.x; irx[1]=v.y; irx[2]=v.z; irx[3]=v.w;
            v = *(const float4*)(Qi  + gstep); qix[0]=v.x; qix[1]=v.y; qix[2]=v.z; qix[3]=v.w;
            v = *(const float4*)(Qa  + gstep); qax[0]=v.x; qax[1]=v.y; qax[2]=v.z; qax[3]=v.w;
            v = *(const float4*)(Ra  + gstep); rax[0]=v.x; rax[1]=v.y; rax[2]=v.z; rax[3]=v.w;
        } else {
#pragma unroll
            for (int j = 0; j < 4; ++j) {
                int gi = gstep + j; bool val = gi < N;
                tox[j] = val ? To[gi]  : 0.f;
                irx[j] = val ? Irr[gi] : 0.f;
                qix[j] = val ? Qi[gi]  : 0.f;
                qax[j] = val ? Qa[gi]  : 0.f;
                rax[j] = val ? Ra[gi]  : 1.f;
            }
        }
        Xf sub = xf_id();
#pragma unroll
        for (int j = 0; j < 4; ++j) {
            if (gstep + j < N) {
                float rR  = __builtin_amdgcn_rcpf(fmaxf(rax[j], 1e-6f));
                float b0  = P.cTo0 * tox[j] + P.cIrr0 * irx[j] + P.cQi0 * qix[j];
                float b1  = P.c1 * fmaf(tox[j], rR, qax[j]) + P.cIrr1 * irx[j] + P.cQi1 * qix[j];
                float M22 = fmaf(P.c1, rR, P.c0);
                float det = fmaf(P.M11, M22, -P.Kx);
                float rd  = __builtin_amdgcn_rcpf(det);
                Xf T;
                T.p =  M22 * rd;
                T.q = -P.M12 * rd;
                T.r = -P.M21 * rd;
                T.s =  P.M11 * rd;
                T.u = T.p * b0 + T.q * b1;
                T.v = T.r * b0 + T.s * b1;
                sub = xf_compose(sub, T);
            }
        }
        storeA(smA, s, sub);
    }
    __syncthreads();

    Xf w = xf_id();
#pragma unroll
    for (int j = 0; j < 4; ++j) w = xf_compose(w, loadA(smA, 4 * t + j));
    Xf incl = block_scan(w, smScan);
    if (t == BLOCK - 1) blkX[blockIdx.x] = incl;
}

// =============== k2: spine scan over block aggregates =======================
__global__ __launch_bounds__(BLOCK) void k_mid(
    const Xf* __restrict__ blkX, float2* __restrict__ blkSt,
    const float* pTin0, int NB)
{
    const int t = threadIdx.x;
    const int ser = (NB + BLOCK - 1) / BLOCK;
    const int base = t * ser;
    Xf acc = xf_id();
    for (int j = 0; j < ser; ++j) {
        int i = base + j;
        if (i < NB) acc = xf_compose(acc, blkX[i]);
    }
    __shared__ float sm[BLOCK * 7];
    block_scan(acc, sm);
    Xf E = xf_id();
    if (t > 0) E = sm_load(sm, t - 1);
    float T0 = *pTin0;
    float x0 = (E.p + E.q) * T0 + E.u;
    float x1 = (E.r + E.s) * T0 + E.v;
    for (int j = 0; j < ser; ++j) {
        int i = base + j;
        if (i < NB) {
            blkSt[i] = make_float2(x0, x1);
            Xf T = blkX[i];
            float n0 = T.p * x0 + T.q * x1 + T.u;
            float n1 = T.r * x0 + T.s * x1 + T.v;
            x0 = n0; x1 = n1;
        }
    }
}

// =============== k3: emit Tin (dense loads, register replay) ================
__global__ __launch_bounds__(BLOCK, 4) void k_emit(
    const float* __restrict__ To, const float* __restrict__ Irr,
    const float* __restrict__ Qi, const float* __restrict__ Qa,
    const float* __restrict__ Ra,
    const float* pRie, const float* pRea, const float* pCin, const float* pCen,
    const float* pAsi, const float* pAse, const float* pAii, const float* pAie,
    const float2* __restrict__ blkSt, float* __restrict__ out, int N)
{
    __shared__ float smA[6400];          // transforms, later reused for states
    __shared__ float smScan[BLOCK * 7];
    const int t = threadIdx.x;
    const int b = blockIdx.x;
    const int blockBase = b * SPAN;
    Par P = make_par(pRie, pRea, pCin, pCen, pAsi, pAse, pAii, pAie);

    float rRv[4][4], b0v[4][4], b1v[4][4];

    // ---------- phase 1: dense loads, sub-chunk transforms ----------
#pragma unroll
    for (int k = 0; k < 4; ++k) {
        const int s = t + BLOCK * k;
        const int gstep = blockBase + s * 4;
        float tox[4], irx[4], qix[4], qax[4], rax[4];
        if (gstep + 4 <= N) {
            float4 v;
            v = *(const float4*)(To  + gstep); tox[0]=v.x; tox[1]=v.y; tox[2]=v.z; tox[3]=v.w;
            v = *(const float4*)(Irr + gstep); irx[0]=v.x; irx[1]=v.y; irx[2]=v.z; irx[3]=v.w;
            v = *(const float4*)(Qi  + gstep); qix[0]=v.x; qix[1]=v.y; qix[2]=v.z; qix[3]=v.w;
            v = *(const float4*)(Qa  + gstep); qax[0]=v.x; qax[1]=v.y; qax[2]=v.z; qax[3]=v.w;
            v = *(const float4*)(Ra  + gstep); rax[0]=v.x; rax[1]=v.y; rax[2]=v.z; rax[3]=v.w;
        } else {
#pragma unroll
            for (int j = 0; j < 4; ++j) {
                int gi = gstep + j; bool val = gi < N;
                tox[j] = val ? To[gi]  : 0.f;
                irx[j] = val ? Irr[gi] : 0.f;
                qix[j] = val ? Qi[gi]  : 0.f;
                qax[j] = val ? Qa[gi]  : 0.f;
                rax[j] = val ? Ra[gi]  : 1.f;
            }
        }
        Xf sub = xf_id();
#pragma unroll
        for (int j = 0; j < 4; ++j) {
            float rR = __builtin_amdgcn_rcpf(fmaxf(rax[j], 1e-6f));
            float b0 = P.cTo0 * tox[j] + P.cIrr0 * irx[j] + P.cQi0 * qix[j];
            float b1 = P.c1 * fmaf(tox[j], rR, qax[j]) + P.cIrr1 * irx[j] + P.cQi1 * qix[j];
            rRv[k][j] = rR; b0v[k][j] = b0; b1v[k][j] = b1;
            if (gstep + j < N) {
                float M22 = fmaf(P.c1, rR, P.c0);
                float det = fmaf(P.M11, M22, -P.Kx);
                float rd  = __builtin_amdgcn_rcpf(det);
                Xf T;
                T.p =  M22 * rd;
                T.q = -P.M12 * rd;
                T.r = -P.M21 * rd;
                T.s =  P.M11 * rd;
                T.u = T.p * b0 + T.q * b1;
                T.v = T.r * b0 + T.s * b1;
                sub = xf_compose(sub, T);
            }
        }
        storeA(smA, s, sub);
    }
    __syncthreads();

    // thread-level compose + intra-block scan -> exclusive thread prefix
    Xf w = xf_id();
#pragma unroll
    for (int j = 0; j < 4; ++j) w = xf_compose(w, loadA(smA, 4 * t + j));
    block_scan(w, smScan);
    Xf E = (t > 0) ? sm_load(smScan, t - 1) : xf_id();

    // block start state -> thread start state -> per-sub-chunk start states
    float2 B = blkSt[b];
    float sx0 = E.p * B.x + E.q * B.y + E.u;
    float sx1 = E.r * B.x + E.s * B.y + E.v;
    float st0[4], st1[4];
#pragma unroll
    for (int j = 0; j < 4; ++j) {
        st0[j] = sx0; st1[j] = sx1;
        Xf S = loadA(smA, 4 * t + j);
        float n0 = S.p * sx0 + S.q * sx1 + S.u;
        float n1 = S.r * sx0 + S.s * sx1 + S.v;
        sx0 = n0; sx1 = n1;
    }
    __syncthreads();   // done reading transforms; reuse smA for states
#pragma unroll
    for (int j = 0; j < 4; ++j) {
        int s = 4 * t + j;
        float* pS = smA + 2 * s + (s >> 3);
        pS[0] = st0[j]; pS[1] = st1[j];
    }
    __syncthreads();

    // ---------- phase 2: replay from registers, dense stores ----------
#pragma unroll
    for (int k = 0; k < 4; ++k) {
        const int s = t + BLOCK * k;
        const float* pS = smA + 2 * s + (s >> 3);
        float x0 = pS[0], x1 = pS[1];
        const int gstep = blockBase + s * 4;
        float ov[4];
#pragma unroll
        for (int j = 0; j < 4; ++j) {
            float rR  = rRv[k][j];
            float M22 = fmaf(P.c1, rR, P.c0);
            float det = fmaf(P.M11, M22, -P.Kx);
            float rd  = __builtin_amdgcn_rcpf(det);
            float r0 = x0 + b0v[k][j];
            float r1 = x1 + b1v[k][j];
            float n0 = (M22 * r0 - P.M12 * r1) * rd;
            float n1 = (P.M11 * r1 - P.M21 * r0) * rd;
            x0 = n0; x1 = n1; ov[j] = n1;
        }
        if (gstep + 4 <= N) {
            float4 o; o.x = ov[0]; o.y = ov[1]; o.z = ov[2]; o.w = ov[3];
            *(float4*)(out + gstep) = o;
        } else {
#pragma unroll
            for (int j = 0; j < 4; ++j) { int gi = gstep + j; if (gi < N) out[gi] = ov[j]; }
        }
    }
}

// ============================  launcher  ====================================
extern "C" void kernel_launch(void* const* d_in, const int* in_sizes, int n_in,
                              void* d_out, int out_size, void* d_ws, size_t ws_size,
                              hipStream_t stream)
{
    (void)n_in; (void)out_size; (void)ws_size;
    const float* pRie = (const float*)d_in[0];
    const float* pRea = (const float*)d_in[1];
    const float* pCin = (const float*)d_in[2];
    const float* pCen = (const float*)d_in[3];
    const float* pAsi = (const float*)d_in[4];
    const float* pAse = (const float*)d_in[5];
    const float* pAii = (const float*)d_in[6];
    const float* pAie = (const float*)d_in[7];
    const float* pTin0 = (const float*)d_in[8];
    const float* To  = (const float*)d_in[9];
    const float* Irr = (const float*)d_in[10];
    const float* Qi  = (const float*)d_in[11];
    const float* Qa  = (const float*)d_in[12];
    const float* Ra  = (const float*)d_in[13];
    float* outp = (float*)d_out;
    int N = in_sizes[9];
    if (N <= 0) return;

    const int NB = (N + SPAN - 1) / SPAN;

    Xf* blkX = (Xf*)d_ws;
    size_t off = ((size_t)NB * sizeof(Xf) + 255) & ~(size_t)255;
    float2* blkSt = (float2*)((char*)d_ws + off);

    k_blocksum<<<NB, BLOCK, 0, stream>>>(To, Irr, Qi, Qa, Ra,
        pRie, pRea, pCin, pCen, pAsi, pAse, pAii, pAie, blkX, N);
    k_mid<<<1, BLOCK, 0, stream>>>(blkX, blkSt, pTin0, NB);
    k_emit<<<NB, BLOCK, 0, stream>>>(To, Irr, Qi, Qa, Ra,
        pRie, pRea, pCin, pCen, pAsi, pAse, pAii, pAie, blkSt, outp, N);
}

// Round 4
// 47.315 us; speedup vs baseline: 5.7865x; 1.0025x over previous
//
#include <hip/hip_runtime.h>

#define BLOCK 256
#define SPAN_LB 8192              // lookback kernel: steps per block (2048 sub-chunks of 4)
#define KITER 8                   // sub-chunks per thread (32 steps/thread)
#define SPAN_FB 4096              // fallback path: steps per block

// Affine transform x -> [[p,q],[r,s]] x + [u,v]
struct Xf { float p, q, r, s, u, v; };

__device__ __forceinline__ Xf xf_id() {
    Xf t; t.p = 1.f; t.q = 0.f; t.r = 0.f; t.s = 1.f; t.u = 0.f; t.v = 0.f;
    return t;
}

// result = L ∘ E  (E applied first, then L)
__device__ __forceinline__ Xf xf_compose(const Xf& E, const Xf& L) {
    Xf o;
    o.p = L.p * E.p + L.q * E.r;
    o.q = L.p * E.q + L.q * E.s;
    o.r = L.r * E.p + L.s * E.r;
    o.s = L.r * E.q + L.s * E.s;
    o.u = L.p * E.u + L.q * E.v + L.u;
    o.v = L.r * E.u + L.s * E.v + L.v;
    return o;
}

struct Par {
    float M11, M12, M21, Kx;
    float c0, c1;              // M22 = c0 + c1*rRia ; c1 = dt/C_in
    float cTo0, cIrr0, cQi0;
    float cIrr1, cQi1;
};

__device__ __forceinline__ Par make_par(
    const float* pRie, const float* pRea, const float* pCin, const float* pCen,
    const float* pAsi, const float* pAse, const float* pAii, const float* pAie)
{
    const float dt = 1800.0f;
    const float GA = 0.76f * 41.3f;
    float R_ie = *pRie, R_ea = *pRea, C_in = *pCin, C_en = *pCen;
    float asi = *pAsi, ase = *pAse, aii = *pAii, aie = *pAie;
    Par P;
    float iRie = 1.0f / R_ie;
    P.M11 = 1.0f + dt * (1.0f / R_ea + iRie) / C_en;
    P.M12 = -(dt * iRie) / C_en;
    P.M21 = -(dt * iRie) / C_in;
    P.Kx  = P.M12 * P.M21;
    P.c1  = dt / C_in;
    P.c0  = 1.0f + P.c1 * iRie;
    P.cTo0  = dt / (C_en * R_ea);
    P.cIrr0 = dt * ase * GA / C_en;
    P.cQi0  = dt * aie / C_en;
    P.cIrr1 = dt * asi * GA / C_in;
    P.cQi1  = dt * aii / C_in;
    return P;
}

// ---- skewed LDS addressing ----
__device__ __forceinline__ void storeA(float* A, int s, const Xf& v) {
    float* b = A + 6 * s + (s >> 2);
    b[0] = v.p; b[1] = v.q; b[2] = v.r; b[3] = v.s; b[4] = v.u; b[5] = v.v;
}
__device__ __forceinline__ Xf loadA(const float* A, int s) {
    const float* b = A + 6 * s + (s >> 2);
    Xf v; v.p = b[0]; v.q = b[1]; v.r = b[2]; v.s = b[3]; v.u = b[4]; v.v = b[5];
    return v;
}
__device__ __forceinline__ void sm_store(float* sm, int i, const Xf& v) {
    float* b = sm + i * 7;
    b[0] = v.p; b[1] = v.q; b[2] = v.r; b[3] = v.s; b[4] = v.u; b[5] = v.v;
}
__device__ __forceinline__ Xf sm_load(const float* sm, int i) {
    const float* b = sm + i * 7;
    Xf v; v.p = b[0]; v.q = b[1]; v.r = b[2]; v.s = b[3]; v.u = b[4]; v.v = b[5];
    return v;
}

// Inclusive Hillis-Steele scan over BLOCK transforms; sm holds inclusives on exit
__device__ __forceinline__ Xf block_scan(Xf v, float* sm) {
    const int t = threadIdx.x;
    sm_store(sm, t, v);
    __syncthreads();
    for (int off = 1; off < BLOCK; off <<= 1) {
        Xf e;
        bool has = (t >= off);
        if (has) e = sm_load(sm, t - off);
        __syncthreads();
        if (has) { v = xf_compose(e, v); sm_store(sm, t, v); }
        __syncthreads();
    }
    return v;
}

// =================== lookback-scan single-pass kernel =======================
__global__ void k_flaginit(unsigned int* __restrict__ flags, int NB) {
    int i = blockIdx.x * blockDim.x + threadIdx.x;
    if (i < NB) flags[i] = 0u;
}

__global__ __launch_bounds__(BLOCK, 2) void k_scan(
    const float* __restrict__ To, const float* __restrict__ Irr,
    const float* __restrict__ Qi, const float* __restrict__ Qa,
    const float* __restrict__ Ra,
    const float* pRie, const float* pRea, const float* pCin, const float* pCen,
    const float* pAsi, const float* pAse, const float* pAii, const float* pAie,
    const float* pTin0,
    unsigned int* __restrict__ flags, float* __restrict__ aggs,   // aggs: NB*6 floats
    float* __restrict__ out, int N)
{
    __shared__ float smA[12800];         // 2048 sub-chunk xfs (51.2 KB), reused for states
    __shared__ float smScan[BLOCK * 7];  // 7 KB
    __shared__ float smE[6];
    const int t = threadIdx.x;
    const int b = blockIdx.x;
    const int blockBase = b * SPAN_LB;
    Par P = make_par(pRie, pRea, pCin, pCen, pAsi, pAse, pAii, pAie);

    float rRv[KITER][4], b0v[KITER][4], b1v[KITER][4];

    // ---------- phase 1: dense loads, sub-chunk transforms ----------
#pragma unroll
    for (int k = 0; k < KITER; ++k) {
        const int s = t + BLOCK * k;            // sub-chunk index 0..2047
        const int gstep = blockBase + s * 4;
        float tox[4], irx[4], qix[4], qax[4], rax[4];
        if (gstep + 4 <= N) {
            float4 v;
            v = *(const float4*)(To  + gstep); tox[0]=v.x; tox[1]=v.y; tox[2]=v.z; tox[3]=v.w;
            v = *(const float4*)(Irr + gstep); irx[0]=v.x; irx[1]=v.y; irx[2]=v.z; irx[3]=v.w;
            v = *(const float4*)(Qi  + gstep); qix[0]=v.x; qix[1]=v.y; qix[2]=v.z; qix[3]=v.w;
            v = *(const float4*)(Qa  + gstep); qax[0]=v.x; qax[1]=v.y; qax[2]=v.z; qax[3]=v.w;
            v = *(const float4*)(Ra  + gstep); rax[0]=v.x; rax[1]=v.y; rax[2]=v.z; rax[3]=v.w;
        } else {
#pragma unroll
            for (int j = 0; j < 4; ++j) {
                int gi = gstep + j; bool val = gi < N;
                tox[j] = val ? To[gi]  : 0.f;
                irx[j] = val ? Irr[gi] : 0.f;
                qix[j] = val ? Qi[gi]  : 0.f;
                qax[j] = val ? Qa[gi]  : 0.f;
                rax[j] = val ? Ra[gi]  : 1.f;
            }
        }
        Xf sub = xf_id();
#pragma unroll
        for (int j = 0; j < 4; ++j) {
            float rR = __builtin_amdgcn_rcpf(fmaxf(rax[j], 1e-6f));
            float b0 = P.cTo0 * tox[j] + P.cIrr0 * irx[j] + P.cQi0 * qix[j];
            float b1 = P.c1 * fmaf(tox[j], rR, qax[j]) + P.cIrr1 * irx[j] + P.cQi1 * qix[j];
            rRv[k][j] = rR; b0v[k][j] = b0; b1v[k][j] = b1;
            if (gstep + j < N) {
                float M22 = fmaf(P.c1, rR, P.c0);
                float det = fmaf(P.M11, M22, -P.Kx);
                float rd  = __builtin_amdgcn_rcpf(det);
                Xf T;
                T.p =  M22 * rd;
                T.q = -P.M12 * rd;
                T.r = -P.M21 * rd;
                T.s =  P.M11 * rd;
                T.u = T.p * b0 + T.q * b1;
                T.v = T.r * b0 + T.s * b1;
                sub = xf_compose(sub, T);
            }
        }
        storeA(smA, s, sub);
    }
    __syncthreads();

    // thread-level compose (KITER sub-chunks) + intra-block scan
    Xf w = xf_id();
#pragma unroll
    for (int j = 0; j < KITER; ++j) w = xf_compose(w, loadA(smA, KITER * t + j));
    Xf incl = block_scan(w, smScan);
    Xf E = (t > 0) ? sm_load(smScan, t - 1) : xf_id();   // exclusive thread prefix

    // publish block aggregate (release, agent scope)
    if (t == BLOCK - 1) {
        float* dst = aggs + 6 * b;
        __hip_atomic_store(dst + 0, incl.p, __ATOMIC_RELAXED, __HIP_MEMORY_SCOPE_AGENT);
        __hip_atomic_store(dst + 1, incl.q, __ATOMIC_RELAXED, __HIP_MEMORY_SCOPE_AGENT);
        __hip_atomic_store(dst + 2, incl.r, __ATOMIC_RELAXED, __HIP_MEMORY_SCOPE_AGENT);
        __hip_atomic_store(dst + 3, incl.s, __ATOMIC_RELAXED, __HIP_MEMORY_SCOPE_AGENT);
        __hip_atomic_store(dst + 4, incl.u, __ATOMIC_RELAXED, __HIP_MEMORY_SCOPE_AGENT);
        __hip_atomic_store(dst + 5, incl.v, __ATOMIC_RELAXED, __HIP_MEMORY_SCOPE_AGENT);
        __hip_atomic_store(&flags[b], 1u, __ATOMIC_RELEASE, __HIP_MEMORY_SCOPE_AGENT);
    }

    // ---------- lookback: wave 0 composes predecessors' aggregates ----------
    if (b == 0) {
        if (t == 0) {
            smE[0] = 1.f; smE[1] = 0.f; smE[2] = 0.f;
            smE[3] = 1.f; smE[4] = 0.f; smE[5] = 0.f;
        }
    } else if (t < 64) {
        // 1. parallel spin until all predecessor flags are set
        for (;;) {
            bool myready = true;
            for (int i = t; i < b; i += 64)
                if (__hip_atomic_load(&flags[i], __ATOMIC_ACQUIRE, __HIP_MEMORY_SCOPE_AGENT) == 0u)
                    myready = false;
            if (__all(myready)) break;
            __builtin_amdgcn_s_sleep(2);
        }
        // 2. ordered compose of aggregates, windows of 64 (low -> high)
        Xf acc = xf_id();
        for (int base = 0; base < b; base += 64) {
            int idx = base + t;
            Xf v = xf_id();
            if (idx < b) {
                const float* src = aggs + 6 * idx;
                v.p = __hip_atomic_load(src + 0, __ATOMIC_RELAXED, __HIP_MEMORY_SCOPE_AGENT);
                v.q = __hip_atomic_load(src + 1, __ATOMIC_RELAXED, __HIP_MEMORY_SCOPE_AGENT);
                v.r = __hip_atomic_load(src + 2, __ATOMIC_RELAXED, __HIP_MEMORY_SCOPE_AGENT);
                v.s = __hip_atomic_load(src + 3, __ATOMIC_RELAXED, __HIP_MEMORY_SCOPE_AGENT);
                v.u = __hip_atomic_load(src + 4, __ATOMIC_RELAXED, __HIP_MEMORY_SCOPE_AGENT);
                v.v = __hip_atomic_load(src + 5, __ATOMIC_RELAXED, __HIP_MEMORY_SCOPE_AGENT);
            }
            // ordered inclusive wave scan (identity padding keeps product correct)
#pragma unroll
            for (int sft = 1; sft < 64; sft <<= 1) {
                Xf u;
                u.p = __shfl_up(v.p, sft, 64);
                u.q = __shfl_up(v.q, sft, 64);
                u.r = __shfl_up(v.r, sft, 64);
                u.s = __shfl_up(v.s, sft, 64);
                u.u = __shfl_up(v.u, sft, 64);
                u.v = __shfl_up(v.v, sft, 64);
                if (t >= sft) v = xf_compose(u, v);
            }
            Xf wacc;
            wacc.p = __shfl(v.p, 63, 64);
            wacc.q = __shfl(v.q, 63, 64);
            wacc.r = __shfl(v.r, 63, 64);
            wacc.s = __shfl(v.s, 63, 64);
            wacc.u = __shfl(v.u, 63, 64);
            wacc.v = __shfl(v.v, 63, 64);
            acc = xf_compose(acc, wacc);  // acc earlier, window later
        }
        if (t == 0) {
            smE[0] = acc.p; smE[1] = acc.q; smE[2] = acc.r;
            smE[3] = acc.s; smE[4] = acc.u; smE[5] = acc.v;
        }
    }
    __syncthreads();

    // block start state
    float T0 = *pTin0;
    float xb0 = (smE[0] + smE[1]) * T0 + smE[4];
    float xb1 = (smE[2] + smE[3]) * T0 + smE[5];

    // thread start state, then per-sub-chunk start states
    float sx0 = E.p * xb0 + E.q * xb1 + E.u;
    float sx1 = E.r * xb0 + E.s * xb1 + E.v;
    float st0[KITER], st1[KITER];
#pragma unroll
    for (int j = 0; j < KITER; ++j) {
        st0[j] = sx0; st1[j] = sx1;
        Xf S = loadA(smA, KITER * t + j);
        float n0 = S.p * sx0 + S.q * sx1 + S.u;
        float n1 = S.r * sx0 + S.s * sx1 + S.v;
        sx0 = n0; sx1 = n1;
    }
    __syncthreads();   // done reading transforms; reuse smA for states
#pragma unroll
    for (int j = 0; j < KITER; ++j) {
        int s = KITER * t + j;
        float* pS = smA + 2 * s + (s >> 3);
        pS[0] = st0[j]; pS[1] = st1[j];
    }
    __syncthreads();

    // ---------- phase 2: replay from registers, dense stores ----------
#pragma unroll
    for (int k = 0; k < KITER; ++k) {
        const int s = t + BLOCK * k;
        const float* pS = smA + 2 * s + (s >> 3);
        float x0 = pS[0], x1 = pS[1];
        const int gstep = blockBase + s * 4;
        float ov[4];
#pragma unroll
        for (int j = 0; j < 4; ++j) {
            float rR  = rRv[k][j];
            float M22 = fmaf(P.c1, rR, P.c0);
            float det = fmaf(P.M11, M22, -P.Kx);
            float rd  = __builtin_amdgcn_rcpf(det);
            float r0 = x0 + b0v[k][j];
            float r1 = x1 + b1v[k][j];
            float n0 = (M22 * r0 - P.M12 * r1) * rd;
            float n1 = (P.M11 * r1 - P.M21 * r0) * rd;
            x0 = n0; x1 = n1; ov[j] = n1;
        }
        if (gstep + 4 <= N) {
            float4 o; o.x = ov[0]; o.y = ov[1]; o.z = ov[2]; o.w = ov[3];
            *(float4*)(out + gstep) = o;
        } else {
#pragma unroll
            for (int j = 0; j < 4; ++j) { int gi = gstep + j; if (gi < N) out[gi] = ov[j]; }
        }
    }
}

// =====================  fallback 3-kernel path (round-3, proven)  ===========
__global__ __launch_bounds__(BLOCK, 4) void k_blocksum(
    const float* __restrict__ To, const float* __restrict__ Irr,
    const float* __restrict__ Qi, const float* __restrict__ Qa,
    const float* __restrict__ Ra,
    const float* pRie, const float* pRea, const float* pCin, const float* pCen,
    const float* pAsi, const float* pAse, const float* pAii, const float* pAie,
    Xf* __restrict__ blkX, int N)
{
    __shared__ float smA[6400];
    __shared__ float smScan[BLOCK * 7];
    const int t = threadIdx.x;
    const int blockBase = blockIdx.x * SPAN_FB;
    Par P = make_par(pRie, pRea, pCin, pCen, pAsi, pAse, pAii, pAie);

#pragma unroll
    for (int k = 0; k < 4; ++k) {
        const int s = t + BLOCK * k;
        const int gstep = blockBase + s * 4;
        float tox[4], irx[4], qix[4], qax[4], rax[4];
        if (gstep + 4 <= N) {
            float4 v;
            v = *(const float4*)(To  + gstep); tox[0]=v.x; tox[1]=v.y; tox[2]=v.z; tox[3]=v.w;
            v = *(const float4*)(Irr + gstep); irx[0]=v.x; irx[1]=v.y; irx[2]=v.z; irx[3]=v.w;
            v = *(const float4*)(Qi  + gstep); qix[0]=v.x; qix[1]=v.y; qix[2]=v.z; qix[3]=v.w;
            v = *(const float4*)(Qa  + gstep); qax[0]=v.x; qax[1]=v.y; qax[2]=v.z; qax[3]=v.w;
            v = *(const float4*)(Ra  + gstep); rax[0]=v.x; rax[1]=v.y; rax[2]=v.z; rax[3]=v.w;
        } else {
#pragma unroll
            for (int j = 0; j < 4; ++j) {
                int gi = gstep + j; bool val = gi < N;
                tox[j] = val ? To[gi]  : 0.f;
                irx[j] = val ? Irr[gi] : 0.f;
                qix[j] = val ? Qi[gi]  : 0.f;
                qax[j] = val ? Qa[gi]  : 0.f;
                rax[j] = val ? Ra[gi]  : 1.f;
            }
        }
        Xf sub = xf_id();
#pragma unroll
        for (int j = 0; j < 4; ++j) {
            if (gstep + j < N) {
                float rR  = __builtin_amdgcn_rcpf(fmaxf(rax[j], 1e-6f));
                float b0  = P.cTo0 * tox[j] + P.cIrr0 * irx[j] + P.cQi0 * qix[j];
                float b1  = P.c1 * fmaf(tox[j], rR, qax[j]) + P.cIrr1 * irx[j] + P.cQi1 * qix[j];
                float M22 = fmaf(P.c1, rR, P.c0);
                float det = fmaf(P.M11, M22, -P.Kx);
                float rd  = __builtin_amdgcn_rcpf(det);
                Xf T;
                T.p =  M22 * rd;
                T.q = -P.M12 * rd;
                T.r = -P.M21 * rd;
                T.s =  P.M11 * rd;
                T.u = T.p * b0 + T.q * b1;
                T.v = T.r * b0 + T.s * b1;
                sub = xf_compose(sub, T);
            }
        }
        storeA(smA, s, sub);
    }
    __syncthreads();

    Xf w = xf_id();
#pragma unroll
    for (int j = 0; j < 4; ++j) w = xf_compose(w, loadA(smA, 4 * t + j));
    Xf incl = block_scan(w, smScan);
    if (t == BLOCK - 1) blkX[blockIdx.x] = incl;
}

__global__ __launch_bounds__(BLOCK) void k_mid(
    const Xf* __restrict__ blkX, float2* __restrict__ blkSt,
    const float* pTin0, int NB)
{
    const int t = threadIdx.x;
    const int ser = (NB + BLOCK - 1) / BLOCK;
    const int base = t * ser;
    Xf acc = xf_id();
    for (int j = 0; j < ser; ++j) {
        int i = base + j;
        if (i < NB) acc = xf_compose(acc, blkX[i]);
    }
    __shared__ float sm[BLOCK * 7];
    block_scan(acc, sm);
    Xf E = xf_id();
    if (t > 0) E = sm_load(sm, t - 1);
    float T0 = *pTin0;
    float x0 = (E.p + E.q) * T0 + E.u;
    float x1 = (E.r + E.s) * T0 + E.v;
    for (int j = 0; j < ser; ++j) {
        int i = base + j;
        if (i < NB) {
            blkSt[i] = make_float2(x0, x1);
            Xf T = blkX[i];
            float n0 = T.p * x0 + T.q * x1 + T.u;
            float n1 = T.r * x0 + T.s * x1 + T.v;
            x0 = n0; x1 = n1;
        }
    }
}

__global__ __launch_bounds__(BLOCK, 4) void k_emit(
    const float* __restrict__ To, const float* __restrict__ Irr,
    const float* __restrict__ Qi, const float* __restrict__ Qa,
    const float* __restrict__ Ra,
    const float* pRie, const float* pRea, const float* pCin, const float* pCen,
    const float* pAsi, const float* pAse, const float* pAii, const float* pAie,
    const float2* __restrict__ blkSt, float* __restrict__ out, int N)
{
    __shared__ float smA[6400];
    __shared__ float smScan[BLOCK * 7];
    const int t = threadIdx.x;
    const int b = blockIdx.x;
    const int blockBase = b * SPAN_FB;
    Par P = make_par(pRie, pRea, pCin, pCen, pAsi, pAse, pAii, pAie);

    float rRv[4][4], b0v[4][4], b1v[4][4];

#pragma unroll
    for (int k = 0; k < 4; ++k) {
        const int s = t + BLOCK * k;
        const int gstep = blockBase + s * 4;
        float tox[4], irx[4], qix[4], qax[4], rax[4];
        if (gstep + 4 <= N) {
            float4 v;
            v = *(const float4*)(To  + gstep); tox[0]=v.x; tox[1]=v.y; tox[2]=v.z; tox[3]=v.w;
            v = *(const float4*)(Irr + gstep); irx[0]=v.x; irx[1]=v.y; irx[2]=v.z; irx[3]=v.w;
            v = *(const float4*)(Qi  + gstep); qix[0]=v.x; qix[1]=v.y; qix[2]=v.z; qix[3]=v.w;
            v = *(const float4*)(Qa  + gstep); qax[0]=v.x; qax[1]=v.y; qax[2]=v.z; qax[3]=v.w;
            v = *(const float4*)(Ra  + gstep); rax[0]=v.x; rax[1]=v.y; rax[2]=v.z; rax[3]=v.w;
        } else {
#pragma unroll
            for (int j = 0; j < 4; ++j) {
                int gi = gstep + j; bool val = gi < N;
                tox[j] = val ? To[gi]  : 0.f;
                irx[j] = val ? Irr[gi] : 0.f;
                qix[j] = val ? Qi[gi]  : 0.f;
                qax[j] = val ? Qa[gi]  : 0.f;
                rax[j] = val ? Ra[gi]  : 1.f;
            }
        }
        Xf sub = xf_id();
#pragma unroll
        for (int j = 0; j < 4; ++j) {
            float rR = __builtin_amdgcn_rcpf(fmaxf(rax[j], 1e-6f));
            float b0 = P.cTo0 * tox[j] + P.cIrr0 * irx[j] + P.cQi0 * qix[j];
            float b1 = P.c1 * fmaf(tox[j], rR, qax[j]) + P.cIrr1 * irx[j] + P.cQi1 * qix[j];
            rRv[k][j] = rR; b0v[k][j] = b0; b1v[k][j] = b1;
            if (gstep + j < N) {
                float M22 = fmaf(P.c1, rR, P.c0);
                float det = fmaf(P.M11, M22, -P.Kx);
                float rd  = __builtin_amdgcn_rcpf(det);
                Xf T;
                T.p =  M22 * rd;
                T.q = -P.M12 * rd;
                T.r = -P.M21 * rd;
                T.s =  P.M11 * rd;
                T.u = T.p * b0 + T.q * b1;
                T.v = T.r * b0 + T.s * b1;
                sub = xf_compose(sub, T);
            }
        }
        storeA(smA, s, sub);
    }
    __syncthreads();

    Xf w = xf_id();
#pragma unroll
    for (int j = 0; j < 4; ++j) w = xf_compose(w, loadA(smA, 4 * t + j));
    block_scan(w, smScan);
    Xf E = (t > 0) ? sm_load(smScan, t - 1) : xf_id();

    float2 B = blkSt[b];
    float sx0 = E.p * B.x + E.q * B.y + E.u;
    float sx1 = E.r * B.x + E.s * B.y + E.v;
    float st0[4], st1[4];
#pragma unroll
    for (int j = 0; j < 4; ++j) {
        st0[j] = sx0; st1[j] = sx1;
        Xf S = loadA(smA, 4 * t + j);
        float n0 = S.p * sx0 + S.q * sx1 + S.u;
        float n1 = S.r * sx0 + S.s * sx1 + S.v;
        sx0 = n0; sx1 = n1;
    }
    __syncthreads();
#pragma unroll
    for (int j = 0; j < 4; ++j) {
        int s = 4 * t + j;
        float* pS = smA + 2 * s + (s >> 3);
        pS[0] = st0[j]; pS[1] = st1[j];
    }
    __syncthreads();

#pragma unroll
    for (int k = 0; k < 4; ++k) {
        const int s = t + BLOCK * k;
        const float* pS = smA + 2 * s + (s >> 3);
        float x0 = pS[0], x1 = pS[1];
        const int gstep = blockBase + s * 4;
        float ov[4];
#pragma unroll
        for (int j = 0; j < 4; ++j) {
            float rR  = rRv[k][j];
            float M22 = fmaf(P.c1, rR, P.c0);
            float det = fmaf(P.M11, M22, -P.Kx);
            float rd  = __builtin_amdgcn_rcpf(det);
            float r0 = x0 + b0v[k][j];
            float r1 = x1 + b1v[k][j];
            float n0 = (M22 * r0 - P.M12 * r1) * rd;
            float n1 = (P.M11 * r1 - P.M21 * r0) * rd;
            x0 = n0; x1 = n1; ov[j] = n1;
        }
        if (gstep + 4 <= N) {
            float4 o; o.x = ov[0]; o.y = ov[1]; o.z = ov[2]; o.w = ov[3];
            *(float4*)(out + gstep) = o;
        } else {
#pragma unroll
            for (int j = 0; j < 4; ++j) { int gi = gstep + j; if (gi < N) out[gi] = ov[j]; }
        }
    }
}

// ============================  launcher  ====================================
extern "C" void kernel_launch(void* const* d_in, const int* in_sizes, int n_in,
                              void* d_out, int out_size, void* d_ws, size_t ws_size,
                              hipStream_t stream)
{
    (void)n_in; (void)out_size; (void)ws_size;
    const float* pRie = (const float*)d_in[0];
    const float* pRea = (const float*)d_in[1];
    const float* pCin = (const float*)d_in[2];
    const float* pCen = (const float*)d_in[3];
    const float* pAsi = (const float*)d_in[4];
    const float* pAse = (const float*)d_in[5];
    const float* pAii = (const float*)d_in[6];
    const float* pAie = (const float*)d_in[7];
    const float* pTin0 = (const float*)d_in[8];
    const float* To  = (const float*)d_in[9];
    const float* Irr = (const float*)d_in[10];
    const float* Qi  = (const float*)d_in[11];
    const float* Qa  = (const float*)d_in[12];
    const float* Ra  = (const float*)d_in[13];
    float* outp = (float*)d_out;
    int N = in_sizes[9];
    if (N <= 0) return;

    const int NB = (N + SPAN_LB - 1) / SPAN_LB;

    // lookback path requires the whole grid co-resident (spin-wait safety)
    int dev = 0;
    hipGetDevice(&dev);
    int numCU = 0;
    hipDeviceGetAttribute(&numCU, hipDeviceAttributeMultiprocessorCount, dev);
    int maxb = 0;
    hipOccupancyMaxActiveBlocksPerMultiprocessor(&maxb, (const void*)k_scan, BLOCK, 0);
    bool ok = (maxb > 0) && ((long long)maxb * (long long)numCU >= (long long)NB);

    if (ok) {
        unsigned int* flags = (unsigned int*)d_ws;
        size_t off = (((size_t)NB * 4) + 255) & ~(size_t)255;
        float* aggs = (float*)((char*)d_ws + off);
        k_flaginit<<<(NB + BLOCK - 1) / BLOCK, BLOCK, 0, stream>>>(flags, NB);
        k_scan<<<NB, BLOCK, 0, stream>>>(To, Irr, Qi, Qa, Ra,
            pRie, pRea, pCin, pCen, pAsi, pAse, pAii, pAie, pTin0,
            flags, aggs, outp, N);
    } else {
        const int NB3 = (N + SPAN_FB - 1) / SPAN_FB;
        Xf* blkX = (Xf*)d_ws;
        size_t off = ((size_t)NB3 * sizeof(Xf) + 255) & ~(size_t)255;
        float2* blkSt = (float2*)((char*)d_ws + off);
        k_blocksum<<<NB3, BLOCK, 0, stream>>>(To, Irr, Qi, Qa, Ra,
            pRie, pRea, pCin, pCen, pAsi, pAse, pAii, pAie, blkX, N);
        k_mid<<<1, BLOCK, 0, stream>>>(blkX, blkSt, pTin0, NB3);
        k_emit<<<NB3, BLOCK, 0, stream>>>(To, Irr, Qi, Qa, Ra,
            pRie, pRea, pCin, pCen, pAsi, pAse, pAii, pAie, blkSt, outp, N);
    }
}